// Round 1
// baseline (797.465 us; speedup 1.0000x reference)
//
#include <hip/hip_runtime.h>

// Problem constants (from reference): B=2, L=2048, H=16, E=64, block_size=256.
#define Bq   2
#define Lq   2048
#define Hq   16
#define Eq   64
#define BSq  256
#define SUB  64     // query rows per workgroup

// d_out layout: output [B][L][H][E] (4194304 floats) then attn [B][H][L][L] (134217728 floats)

// One wg = (b, h, qb, sub): 64 query rows of one diagonal block, all 256 keys of that block.
// 256 threads: lane r = t&63 <-> query row, part = t>>6 <-> 64-key partition (wave-uniform).
// Dynamic LDS layout (133,632 B):
//   S[64][257]  fp32 scores->exp (stride 257: bank=(r+s)%32, 2-way = free)  65792 B
//   KV[4096] float4: K tile, then V tile, then output-reduction scratch     65536 B
//   mred[4][64], lred[4][64], invl[64]                                       2304 B
__global__ __launch_bounds__(256, 1)
void sparse_attn(const float* __restrict__ qp,
                 const float* __restrict__ kp,
                 const float* __restrict__ vp,
                 float* __restrict__ outp)
{
    extern __shared__ float smem[];
    float (*S)[257] = (float (*)[257])smem;            // 64*257 floats
    float4* KV      = (float4*)(smem + 64*257);        // 4096 float4
    float*  mred    = smem + 64*257 + 4096*4;          // [4][64]
    float*  lred    = mred + 256;                      // [4][64]
    float*  invl    = lred + 256;                      // [64]

    const int w   = blockIdx.x;
    const int sub = w & 3;
    const int qb  = (w >> 2) & 7;
    const int h   = (w >> 5) & 15;
    const int b   = w >> 9;
    const int R0  = qb * BSq + sub * SUB;

    const int t    = threadIdx.x;
    const int r    = t & 63;
    const int part = t >> 6;   // wave-uniform

    float* attn = outp + (size_t)Bq * Lq * Hq * Eq;

    // ---- P0: stage K tile [256][64] into KV (coalesced); Q row -> 64 VGPRs ----
    const float* kbase = kp + (((size_t)b * Lq + qb * BSq) * Hq + h) * Eq;
    #pragma unroll
    for (int i = 0; i < 16; ++i) {
        int idx = i * 256 + t;          // 0..4095 float4s
        int s   = idx >> 4;
        int e4  = idx & 15;
        KV[idx] = *(const float4*)(kbase + (size_t)s * (Hq * Eq) + e4 * 4);
    }
    const float* qrow = qp + (((size_t)b * Lq + R0 + r) * Hq + h) * Eq;
    float4 qreg[16];
    #pragma unroll
    for (int j = 0; j < 16; ++j) qreg[j] = *(const float4*)(qrow + 4 * j);
    __syncthreads();

    // ---- P1: scores for this part's 64 keys; K rows are wave-uniform LDS broadcasts ----
    float lmax = -3.4e38f;
    #pragma unroll 2
    for (int sl = 0; sl < 64; ++sl) {
        int s = part * 64 + sl;
        float p0 = 0.f, p1 = 0.f, p2 = 0.f, p3 = 0.f;  // 4 chains: hide FMA latency
        #pragma unroll
        for (int j = 0; j < 16; ++j) {
            float4 kv = KV[s * 16 + j];
            p0 = fmaf(qreg[j].x, kv.x, p0);
            p1 = fmaf(qreg[j].y, kv.y, p1);
            p2 = fmaf(qreg[j].z, kv.z, p2);
            p3 = fmaf(qreg[j].w, kv.w, p3);
        }
        float sc = (p0 + p1) + (p2 + p3);
        S[r][s] = sc;
        lmax = fmaxf(lmax, sc);
    }
    mred[part * 64 + r] = lmax;
    __syncthreads();

    // ---- P2: stage V over K (barrier above guarantees K reads done); softmax pass ----
    const float* vbase = vp + (((size_t)b * Lq + qb * BSq) * Hq + h) * Eq;
    #pragma unroll
    for (int i = 0; i < 16; ++i) {
        int idx = i * 256 + t;
        int s   = idx >> 4;
        int e4  = idx & 15;
        KV[idx] = *(const float4*)(vbase + (size_t)s * (Hq * Eq) + e4 * 4);
    }
    float m = fmaxf(fmaxf(mred[r], mred[64 + r]), fmaxf(mred[128 + r], mred[192 + r]));
    float lsum = 0.f;
    #pragma unroll 2
    for (int sl = 0; sl < 64; ++sl) {
        int s = part * 64 + sl;
        float e = __expf(S[r][s] - m);
        S[r][s] = e;                 // store unnormalized p
        lsum += e;
    }
    lred[part * 64 + r] = lsum;
    __syncthreads();
    const float linv = 1.0f / (lred[r] + lred[64 + r] + lred[128 + r] + lred[192 + r]);
    if (part == 0) invl[r] = linv;   // made visible to all by the P3-end barrier

    // ---- P3: partial PV over this part's keys (unnormalized); V rows broadcast ----
    float4 acc[16];
    #pragma unroll
    for (int j = 0; j < 16; ++j) acc[j] = make_float4(0.f, 0.f, 0.f, 0.f);
    #pragma unroll 2
    for (int sl = 0; sl < 64; ++sl) {
        int s = part * 64 + sl;
        float p = S[r][s];
        #pragma unroll
        for (int j = 0; j < 16; ++j) {
            float4 vv = KV[s * 16 + j];
            acc[j].x = fmaf(p, vv.x, acc[j].x);
            acc[j].y = fmaf(p, vv.y, acc[j].y);
            acc[j].z = fmaf(p, vv.z, acc[j].z);
            acc[j].w = fmaf(p, vv.w, acc[j].w);
        }
    }
    __syncthreads();   // all waves done reading V from KV

    // ---- P4: cross-part output reduction through KV scratch, write output ----
    float* red = (float*)KV;   // 3 * 64 * 65 = 12480 floats <= 16384 avail
    if (part != 0) {
        float* dst = red + (size_t)(part - 1) * 4160 + r * 65;  // stride 65: 2-way banks
        #pragma unroll
        for (int j = 0; j < 16; ++j) {
            dst[4 * j + 0] = acc[j].x;
            dst[4 * j + 1] = acc[j].y;
            dst[4 * j + 2] = acc[j].z;
            dst[4 * j + 3] = acc[j].w;
        }
    }
    __syncthreads();
    if (part == 0) {
        float* orow = outp + (((size_t)b * Lq + R0 + r) * Hq + h) * Eq;
        const float* s0 = red + r * 65;
        const float* s1 = red + 4160 + r * 65;
        const float* s2 = red + 8320 + r * 65;
        #pragma unroll
        for (int j = 0; j < 16; ++j) {
            float4 val = acc[j];
            val.x = (val.x + s0[4 * j + 0] + s1[4 * j + 0] + s2[4 * j + 0]) * linv;
            val.y = (val.y + s0[4 * j + 1] + s1[4 * j + 1] + s2[4 * j + 1]) * linv;
            val.z = (val.z + s0[4 * j + 2] + s1[4 * j + 2] + s2[4 * j + 2]) * linv;
            val.w = (val.w + s0[4 * j + 3] + s1[4 * j + 3] + s2[4 * j + 3]) * linv;
            *(float4*)(orow + 4 * j) = val;
        }
    }

    // ---- P5: attn writes, all coalesced, no trailing barrier (drain overlaps next wg) ----
    float* ablock = attn + (((size_t)b * Hq + h) * Lq + R0) * Lq;  // rows R0..R0+63
    // in-block 64 x 256: lane-contiguous stores, S read is 2-way-bank (free)
    #pragma unroll 2
    for (int i = 0; i < 64; ++i) {
        ablock[(size_t)i * Lq + qb * BSq + t] = S[i][t] * invl[i];
    }
    // off-block zeros: 64 rows x 1792 cols as float4 (the dominant 448 MiB stream)
    float4* abase4 = (float4*)ablock;
    const int qb64 = qb * 64;
    const float4 z = make_float4(0.f, 0.f, 0.f, 0.f);
    #pragma unroll 2
    for (int i = 0; i < 112; ++i) {
        int f   = i * 256 + t;           // 0..28671
        int row = f / 448;               // magic-mul div
        int j   = f - row * 448;
        int c4  = (j < qb64) ? j : j + 64;  // skip the diagonal 64 float4s
        abase4[(size_t)row * 512 + c4] = z;
    }
}

extern "C" void kernel_launch(void* const* d_in, const int* in_sizes, int n_in,
                              void* d_out, int out_size, void* d_ws, size_t ws_size,
                              hipStream_t stream) {
    const float* q = (const float*)d_in[0];
    const float* k = (const float*)d_in[1];
    const float* v = (const float*)d_in[2];
    float* out = (float*)d_out;

    const size_t lds_bytes = (64 * 257 + 4096 * 4 + 256 + 256 + 64) * sizeof(float); // 133,632
    // Opt in to >64 KiB dynamic LDS (idempotent, host-side, capture-safe: not a stream op).
    (void)hipFuncSetAttribute((const void*)sparse_attn,
                              hipFuncAttributeMaxDynamicSharedMemorySize,
                              (int)lds_bytes);

    dim3 grid(Bq * Hq * 8 * 4);   // 1024 wgs
    dim3 block(256);
    hipLaunchKernelGGL(sparse_attn, grid, block, lds_bytes, stream, q, k, v, out);
}

// Round 2
// 754.414 us; speedup vs baseline: 1.0571x; 1.0571x over previous
//
#include <hip/hip_runtime.h>

#define Bq 2
#define Lq 2048
#define Hq 16
#define Eq 64
#define HE (Hq * Eq)   // 1024 floats between consecutive l for fixed (h)

// LDS layout (floats unless noted), total 74,752 B -> 2 wg/CU (149.5 <= 160 KB):
//   Qs  [64][68]          17,408 B   (row stride 68: rg-distinct reads hit banks 4*rg)
//   KVs [5120]            20,480 B   K rounds: [256 keys][20] (16 dims + pad)
//                                    V rounds: [64 keys][16 f4] XOR-swizzled (d4 ^ (key>>3))
//   red [512]              2,048 B   mred[4][64] / lred[4][64]
//   Sp  ushort[64][272]   34,816 B   normalized p, bf16, PERMUTED cols:
//                                    col (w*64+cg+8j) stored at w*64+cg*8+j
#define QS_STRIDE 68
#define KV_OFF    4352
#define RED_OFF   9472
#define SP_OFF    9984
#define SP_STRIDE 272

__device__ __forceinline__ unsigned short f2bf(float x) {
    unsigned u = __float_as_uint(x);
    return (unsigned short)((u + 0x7fffu + ((u >> 16) & 1u)) >> 16);  // RNE
}
__device__ __forceinline__ float bf2f(unsigned short s) {
    return __uint_as_float(((unsigned)s) << 16);
}

// 448 off-diagonal float4 columns per row, 64 rows = 28672 float4 zeros per wg,
// split into 8 chunks of 14 per thread, issued between compute phases.
__device__ __forceinline__ void fill_chunk(float4* __restrict__ abase4, int qb64, int t, int c) {
    const float4 z = make_float4(0.f, 0.f, 0.f, 0.f);
    #pragma unroll
    for (int i = 0; i < 14; ++i) {
        int f   = (c * 14 + i) * 256 + t;     // [0, 28672)
        int row = f / 448;                    // magic-mul
        int j   = f - row * 448;
        int c4  = (j < qb64) ? j : j + 64;    // skip diagonal 64 float4s
        abase4[(size_t)row * 512 + c4] = z;
    }
}

__global__ __launch_bounds__(256, 2)
void sparse_attn(const float* __restrict__ qp, const float* __restrict__ kp,
                 const float* __restrict__ vp, float* __restrict__ outp)
{
    extern __shared__ float smem[];
    float* Qs  = smem;
    float* KVs = smem + KV_OFF;
    float* red = smem + RED_OFF;
    unsigned short* Sp = (unsigned short*)(smem + SP_OFF);

    const int w3  = blockIdx.x;
    const int sub = w3 & 3, qb = (w3 >> 2) & 7, h = (w3 >> 5) & 15, b = w3 >> 9;
    const int R0  = qb * 256 + sub * 64;

    const int t = threadIdx.x;
    const int wv = t >> 6, lane = t & 63, rg = lane & 7, cg = lane >> 3;

    const float* qbase = qp + ((size_t)(b * Lq + R0) * Hq + h) * Eq;
    const float* kbase = kp + ((size_t)(b * Lq + qb * 256) * Hq + h) * Eq;
    const float* vbase = vp + ((size_t)(b * Lq + qb * 256) * Hq + h) * Eq;
    float* attn   = outp + (size_t)Bq * Lq * Hq * Eq;
    float* ablock = attn + ((size_t)(b * Hq + h) * Lq + R0) * Lq;
    float4* abase4 = (float4*)ablock;
    const int qb64 = qb * 64;

    // ---- stage Q (all 64 dims) + K round 0 (dims 0..15) ----
    #pragma unroll
    for (int i = 0; i < 4; ++i) {
        int idx = i * 256 + t, row = idx >> 4, e4 = idx & 15;
        *(float4*)&Qs[row * QS_STRIDE + e4 * 4] =
            *(const float4*)(qbase + (size_t)row * HE + e4 * 4);
    }
    #pragma unroll
    for (int i = 0; i < 4; ++i) {
        int idx = i * 256 + t, key = idx >> 2, e4 = idx & 3;
        *(float4*)&KVs[key * 20 + e4 * 4] =
            *(const float4*)(kbase + (size_t)key * HE + e4 * 4);
    }
    __syncthreads();

    // ---- P1: QK^T, lane tile 8 rows (rg+8i) x 8 cols (wv*64+cg+8j), 4 dim-rounds ----
    float sc[8][8];
    #pragma unroll
    for (int i = 0; i < 8; ++i)
        #pragma unroll
        for (int j = 0; j < 8; ++j) sc[i][j] = 0.f;

    for (int rd = 0; rd < 4; ++rd) {
        #pragma unroll
        for (int kc = 0; kc < 4; ++kc) {
            float4 qf[8], kf[8];
            #pragma unroll
            for (int i = 0; i < 8; ++i)
                qf[i] = *(float4*)&Qs[(rg + 8 * i) * QS_STRIDE + rd * 16 + kc * 4];
            #pragma unroll
            for (int j = 0; j < 8; ++j)
                kf[j] = *(float4*)&KVs[(wv * 64 + cg + 8 * j) * 20 + kc * 4];
            #pragma unroll
            for (int i = 0; i < 8; ++i)
                #pragma unroll
                for (int j = 0; j < 8; ++j)
                    sc[i][j] = fmaf(qf[i].x, kf[j].x,
                               fmaf(qf[i].y, kf[j].y,
                               fmaf(qf[i].z, kf[j].z,
                               fmaf(qf[i].w, kf[j].w, sc[i][j]))));
        }
        if (rd < 3) {
            __syncthreads();
            #pragma unroll
            for (int i = 0; i < 4; ++i) {
                int idx = i * 256 + t, key = idx >> 2, e4 = idx & 3;
                *(float4*)&KVs[key * 20 + e4 * 4] =
                    *(const float4*)(kbase + (size_t)key * HE + (rd + 1) * 16 + e4 * 4);
            }
            fill_chunk(abase4, qb64, t, rd);   // chunks 0..2
            __syncthreads();
        }
    }

    // ---- softmax fully in registers + tiny LDS cross-wave exchange ----
    float mrow[8];
    #pragma unroll
    for (int i = 0; i < 8; ++i) {
        float m = sc[i][0];
        #pragma unroll
        for (int j = 1; j < 8; ++j) m = fmaxf(m, sc[i][j]);
        m = fmaxf(m, __shfl_xor(m, 8));
        m = fmaxf(m, __shfl_xor(m, 16));
        m = fmaxf(m, __shfl_xor(m, 32));
        mrow[i] = m;
    }
    if (cg == 0) {
        #pragma unroll
        for (int i = 0; i < 8; ++i) red[wv * 64 + rg + 8 * i] = mrow[i];
    }
    __syncthreads();   // b1: mred visible; all waves done with K tile

    // stage V round 0 into KVs (dead K region), overlapping the exp work below
    #pragma unroll
    for (int i = 0; i < 4; ++i) {
        int idx = i * 256 + t, k63 = idx >> 4, e4 = idx & 15;
        *(float4*)&KVs[(k63 * 16 + (e4 ^ (k63 >> 3))) * 4] =
            *(const float4*)(vbase + (size_t)k63 * HE + e4 * 4);
    }

    float lrow[8];
    #pragma unroll
    for (int i = 0; i < 8; ++i) {
        int r = rg + 8 * i;
        float m = fmaxf(fmaxf(red[r], red[64 + r]), fmaxf(red[128 + r], red[192 + r]));
        float l = 0.f;
        #pragma unroll
        for (int j = 0; j < 8; ++j) {
            float e = __expf(sc[i][j] - m);
            sc[i][j] = e;
            l += e;
        }
        l += __shfl_xor(l, 8);
        l += __shfl_xor(l, 16);
        l += __shfl_xor(l, 32);
        lrow[i] = l;
    }
    if (cg == 0) {
        #pragma unroll
        for (int i = 0; i < 8; ++i) red[256 + wv * 64 + rg + 8 * i] = lrow[i];
    }
    __syncthreads();   // b2: lred + V0 visible

    // normalize in-register, pack bf16, write Sp (contiguous b128 per row)
    #pragma unroll
    for (int i = 0; i < 8; ++i) {
        int r = rg + 8 * i;
        float linv = 1.0f / (red[256 + r] + red[320 + r] + red[384 + r] + red[448 + r]);
        unsigned u0 = (unsigned)f2bf(sc[i][0] * linv) | ((unsigned)f2bf(sc[i][1] * linv) << 16);
        unsigned u1 = (unsigned)f2bf(sc[i][2] * linv) | ((unsigned)f2bf(sc[i][3] * linv) << 16);
        unsigned u2 = (unsigned)f2bf(sc[i][4] * linv) | ((unsigned)f2bf(sc[i][5] * linv) << 16);
        unsigned u3 = (unsigned)f2bf(sc[i][6] * linv) | ((unsigned)f2bf(sc[i][7] * linv) << 16);
        *(uint4*)&Sp[r * SP_STRIDE + wv * 64 + cg * 8] = make_uint4(u0, u1, u2, u3);
    }
    fill_chunk(abase4, qb64, t, 3);
    __syncthreads();   // b3: Sp visible

    // ---- P3: PV. wave wv owns rows 16wv..+15; lane tile 4 rows (r4+4i) x 4 dims (d4*4..) ----
    const int r4 = lane & 3, d4 = lane >> 2;
    float4 acc[4];
    #pragma unroll
    for (int i = 0; i < 4; ++i) acc[i] = make_float4(0.f, 0.f, 0.f, 0.f);

    for (int kb = 0; kb < 4; ++kb) {
        if (kb) {
            __syncthreads();
            #pragma unroll
            for (int i = 0; i < 4; ++i) {
                int idx = i * 256 + t, k63 = idx >> 4, e4 = idx & 15;
                *(float4*)&KVs[(k63 * 16 + (e4 ^ (k63 >> 3))) * 4] =
                    *(const float4*)(vbase + (size_t)(kb * 64 + k63) * HE + e4 * 4);
            }
            fill_chunk(abase4, qb64, t, 3 + kb);   // chunks 4..6
            __syncthreads();
        }
        #pragma unroll
        for (int c = 0; c < 8; ++c) {
            float pv[4][8];
            #pragma unroll
            for (int i = 0; i < 4; ++i) {
                int row = 16 * wv + r4 + 4 * i;
                uint4 pw = *(uint4*)&Sp[row * SP_STRIDE + kb * 64 + c * 8];
                pv[i][0] = __uint_as_float(pw.x << 16);
                pv[i][1] = __uint_as_float(pw.x & 0xffff0000u);
                pv[i][2] = __uint_as_float(pw.y << 16);
                pv[i][3] = __uint_as_float(pw.y & 0xffff0000u);
                pv[i][4] = __uint_as_float(pw.z << 16);
                pv[i][5] = __uint_as_float(pw.z & 0xffff0000u);
                pv[i][6] = __uint_as_float(pw.w << 16);
                pv[i][7] = __uint_as_float(pw.w & 0xffff0000u);
            }
            #pragma unroll
            for (int k = 0; k < 8; ++k) {
                float4 vv = *(float4*)&KVs[((c + 8 * k) * 16 + (d4 ^ k)) * 4];
                #pragma unroll
                for (int i = 0; i < 4; ++i) {
                    acc[i].x = fmaf(pv[i][k], vv.x, acc[i].x);
                    acc[i].y = fmaf(pv[i][k], vv.y, acc[i].y);
                    acc[i].z = fmaf(pv[i][k], vv.z, acc[i].z);
                    acc[i].w = fmaf(pv[i][k], vv.w, acc[i].w);
                }
            }
        }
    }

    // ---- output write: p already normalized, no scaling needed ----
    #pragma unroll
    for (int i = 0; i < 4; ++i) {
        int row = 16 * wv + r4 + 4 * i;
        *(float4*)(outp + ((size_t)(b * Lq + R0 + row) * Hq + h) * Eq + d4 * 4) = acc[i];
    }

    // ---- diagonal attn block: coalesced float4 stores, gather from permuted Sp ----
    #pragma unroll 4
    for (int i = 0; i < 16; ++i) {
        int idx = i * 256 + t, row = idx >> 6, c4 = idx & 63, c = c4 * 4;
        int basep = row * SP_STRIDE + (c & 0xC0) + ((c >> 3) & 7);
        int c7 = c & 7;   // 0 or 4
        float4 v;
        v.x = bf2f(Sp[basep + (c7 + 0) * 8]);
        v.y = bf2f(Sp[basep + (c7 + 1) * 8]);
        v.z = bf2f(Sp[basep + (c7 + 2) * 8]);
        v.w = bf2f(Sp[basep + (c7 + 3) * 8]);
        *(float4*)(ablock + (size_t)row * Lq + qb * 256 + c) = v;
    }
    fill_chunk(abase4, qb64, t, 7);   // final zero chunk; no trailing barrier
}

extern "C" void kernel_launch(void* const* d_in, const int* in_sizes, int n_in,
                              void* d_out, int out_size, void* d_ws, size_t ws_size,
                              hipStream_t stream) {
    const float* q = (const float*)d_in[0];
    const float* k = (const float*)d_in[1];
    const float* v = (const float*)d_in[2];
    float* out = (float*)d_out;

    const size_t lds_bytes = SP_OFF * sizeof(float) + 64 * SP_STRIDE * sizeof(unsigned short); // 74,752
    (void)hipFuncSetAttribute((const void*)sparse_attn,
                              hipFuncAttributeMaxDynamicSharedMemorySize,
                              (int)lds_bytes);

    dim3 grid(Bq * Hq * 8 * 4);   // 1024 wgs: (b,h,qb,sub)
    dim3 block(256);
    hipLaunchKernelGGL(sparse_attn, grid, block, lds_bytes, stream, q, k, v, out);
}

// Round 4
// 730.012 us; speedup vs baseline: 1.0924x; 1.0334x over previous
//
#include <hip/hip_runtime.h>

#define Bq 2
#define Lq 2048
#define Hq 16
#define Eq 64
#define HE (Hq * Eq)   // 1024 floats between consecutive l for fixed (h)

// LDS layout (floats unless noted), total 74,752 B -> 2 wg/CU (149.5 <= 160 KB):
//   Qs  [64][68]          17,408 B   (row stride 68)
//   KVs [5120]            20,480 B   K rounds: [256 keys][20]; V rounds: [64][16 f4] XOR-swizzled
//   red [512]              2,048 B   mred[4][64] / lred[4][64]
//   Sp  ushort[64][272]   34,816 B   normalized p, bf16, permuted cols
#define QS_STRIDE 68
#define KV_OFF    4352
#define RED_OFF   9472
#define SP_OFF    9984
#define SP_STRIDE 272

// native clang vector type: __builtin_nontemporal_store requires it
typedef float  nfloat4 __attribute__((ext_vector_type(4)));

__device__ __forceinline__ void nt_store4(float* p, float x, float y, float z, float w) {
    nfloat4 v = {x, y, z, w};
    __builtin_nontemporal_store(v, (nfloat4*)p);
}

__device__ __forceinline__ unsigned short f2bf(float x) {
    unsigned u = __float_as_uint(x);
    return (unsigned short)((u + 0x7fffu + ((u >> 16) & 1u)) >> 16);  // RNE
}
__device__ __forceinline__ float bf2f(unsigned short s) {
    return __uint_as_float(((unsigned)s) << 16);
}

__global__ __launch_bounds__(256, 2)
void sparse_attn(const float* __restrict__ qp, const float* __restrict__ kp,
                 const float* __restrict__ vp, float* __restrict__ outp)
{
    extern __shared__ float smem[];
    float* Qs  = smem;
    float* KVs = smem + KV_OFF;
    float* red = smem + RED_OFF;
    unsigned short* Sp = (unsigned short*)(smem + SP_OFF);

    const int w3  = blockIdx.x;
    const int sub = w3 & 3, qb = (w3 >> 2) & 7, h = (w3 >> 5) & 15, b = w3 >> 9;
    const int R0  = qb * 256 + sub * 64;

    const int t = threadIdx.x;
    const int wv = t >> 6, lane = t & 63, rg = lane & 7, cg = lane >> 3;

    const float* qbase = qp + ((size_t)(b * Lq + R0) * Hq + h) * Eq;
    const float* kbase = kp + ((size_t)(b * Lq + qb * 256) * Hq + h) * Eq;
    const float* vbase = vp + ((size_t)(b * Lq + qb * 256) * Hq + h) * Eq;
    float* attn   = outp + (size_t)Bq * Lq * Hq * Eq;
    float* ablock = attn + ((size_t)(b * Hq + h) * Lq + R0) * Lq;
    const int qb64 = qb * 64;

    // ---- stage Q (all 64 dims) + K round 0 (dims 0..15) ----
    #pragma unroll
    for (int i = 0; i < 4; ++i) {
        int idx = i * 256 + t, row = idx >> 4, e4 = idx & 15;
        *(float4*)&Qs[row * QS_STRIDE + e4 * 4] =
            *(const float4*)(qbase + (size_t)row * HE + e4 * 4);
    }
    #pragma unroll
    for (int i = 0; i < 4; ++i) {
        int idx = i * 256 + t, key = idx >> 2, e4 = idx & 3;
        *(float4*)&KVs[key * 20 + e4 * 4] =
            *(const float4*)(kbase + (size_t)key * HE + e4 * 4);
    }
    __syncthreads();

    // ---- P1: QK^T, lane tile 8 rows (rg+8i) x 8 cols (wv*64+cg+8j), 4 dim-rounds ----
    float sc[8][8];
    #pragma unroll
    for (int i = 0; i < 8; ++i)
        #pragma unroll
        for (int j = 0; j < 8; ++j) sc[i][j] = 0.f;

    for (int rd = 0; rd < 4; ++rd) {
        #pragma unroll
        for (int kc = 0; kc < 4; ++kc) {
            float4 qf[8], kf[8];
            #pragma unroll
            for (int i = 0; i < 8; ++i)
                qf[i] = *(float4*)&Qs[(rg + 8 * i) * QS_STRIDE + rd * 16 + kc * 4];
            #pragma unroll
            for (int j = 0; j < 8; ++j)
                kf[j] = *(float4*)&KVs[(wv * 64 + cg + 8 * j) * 20 + kc * 4];
            #pragma unroll
            for (int i = 0; i < 8; ++i)
                #pragma unroll
                for (int j = 0; j < 8; ++j)
                    sc[i][j] = fmaf(qf[i].x, kf[j].x,
                               fmaf(qf[i].y, kf[j].y,
                               fmaf(qf[i].z, kf[j].z,
                               fmaf(qf[i].w, kf[j].w, sc[i][j]))));
        }
        if (rd < 3) {
            __syncthreads();
            #pragma unroll
            for (int i = 0; i < 4; ++i) {
                int idx = i * 256 + t, key = idx >> 2, e4 = idx & 3;
                *(float4*)&KVs[key * 20 + e4 * 4] =
                    *(const float4*)(kbase + (size_t)key * HE + (rd + 1) * 16 + e4 * 4);
            }
            __syncthreads();
        }
    }

    // ---- softmax fully in registers + tiny LDS cross-wave exchange ----
    float mrow[8];
    #pragma unroll
    for (int i = 0; i < 8; ++i) {
        float m = sc[i][0];
        #pragma unroll
        for (int j = 1; j < 8; ++j) m = fmaxf(m, sc[i][j]);
        m = fmaxf(m, __shfl_xor(m, 8));
        m = fmaxf(m, __shfl_xor(m, 16));
        m = fmaxf(m, __shfl_xor(m, 32));
        mrow[i] = m;
    }
    if (cg == 0) {
        #pragma unroll
        for (int i = 0; i < 8; ++i) red[wv * 64 + rg + 8 * i] = mrow[i];
    }
    __syncthreads();   // b1: mred visible; all waves done with K tile

    // stage V round 0 into KVs (dead K region), overlapping the exp work below
    #pragma unroll
    for (int i = 0; i < 4; ++i) {
        int idx = i * 256 + t, k63 = idx >> 4, e4 = idx & 15;
        *(float4*)&KVs[(k63 * 16 + (e4 ^ (k63 >> 3))) * 4] =
            *(const float4*)(vbase + (size_t)k63 * HE + e4 * 4);
    }

    float lrow[8];
    #pragma unroll
    for (int i = 0; i < 8; ++i) {
        int r = rg + 8 * i;
        float m = fmaxf(fmaxf(red[r], red[64 + r]), fmaxf(red[128 + r], red[192 + r]));
        float l = 0.f;
        #pragma unroll
        for (int j = 0; j < 8; ++j) {
            float e = __expf(sc[i][j] - m);
            sc[i][j] = e;
            l += e;
        }
        l += __shfl_xor(l, 8);
        l += __shfl_xor(l, 16);
        l += __shfl_xor(l, 32);
        lrow[i] = l;
    }
    if (cg == 0) {
        #pragma unroll
        for (int i = 0; i < 8; ++i) red[256 + wv * 64 + rg + 8 * i] = lrow[i];
    }
    __syncthreads();   // b2: lred + V0 visible

    // normalize in-register, pack bf16, write Sp (contiguous b128 per row)
    #pragma unroll
    for (int i = 0; i < 8; ++i) {
        int r = rg + 8 * i;
        float linv = 1.0f / (red[256 + r] + red[320 + r] + red[384 + r] + red[448 + r]);
        unsigned u0 = (unsigned)f2bf(sc[i][0] * linv) | ((unsigned)f2bf(sc[i][1] * linv) << 16);
        unsigned u1 = (unsigned)f2bf(sc[i][2] * linv) | ((unsigned)f2bf(sc[i][3] * linv) << 16);
        unsigned u2 = (unsigned)f2bf(sc[i][4] * linv) | ((unsigned)f2bf(sc[i][5] * linv) << 16);
        unsigned u3 = (unsigned)f2bf(sc[i][6] * linv) | ((unsigned)f2bf(sc[i][7] * linv) << 16);
        *(uint4*)&Sp[r * SP_STRIDE + wv * 64 + cg * 8] = make_uint4(u0, u1, u2, u3);
    }
    __syncthreads();   // b3: Sp visible

    // ---- P3: PV. wave wv owns rows 16wv..+15; lane tile 4 rows x 4 dims ----
    const int r4 = lane & 3, d4 = lane >> 2;
    float4 acc[4];
    #pragma unroll
    for (int i = 0; i < 4; ++i) acc[i] = make_float4(0.f, 0.f, 0.f, 0.f);

    for (int kb = 0; kb < 4; ++kb) {
        if (kb) {
            __syncthreads();
            #pragma unroll
            for (int i = 0; i < 4; ++i) {
                int idx = i * 256 + t, k63 = idx >> 4, e4 = idx & 15;
                *(float4*)&KVs[(k63 * 16 + (e4 ^ (k63 >> 3))) * 4] =
                    *(const float4*)(vbase + (size_t)(kb * 64 + k63) * HE + e4 * 4);
            }
            __syncthreads();
        }
        #pragma unroll
        for (int c = 0; c < 8; ++c) {
            float pv[4][8];
            #pragma unroll
            for (int i = 0; i < 4; ++i) {
                int row = 16 * wv + r4 + 4 * i;
                uint4 pw = *(uint4*)&Sp[row * SP_STRIDE + kb * 64 + c * 8];
                pv[i][0] = __uint_as_float(pw.x << 16);
                pv[i][1] = __uint_as_float(pw.x & 0xffff0000u);
                pv[i][2] = __uint_as_float(pw.y << 16);
                pv[i][3] = __uint_as_float(pw.y & 0xffff0000u);
                pv[i][4] = __uint_as_float(pw.z << 16);
                pv[i][5] = __uint_as_float(pw.z & 0xffff0000u);
                pv[i][6] = __uint_as_float(pw.w << 16);
                pv[i][7] = __uint_as_float(pw.w & 0xffff0000u);
            }
            #pragma unroll
            for (int k = 0; k < 8; ++k) {
                float4 vv = *(float4*)&KVs[((c + 8 * k) * 16 + (d4 ^ k)) * 4];
                #pragma unroll
                for (int i = 0; i < 4; ++i) {
                    acc[i].x = fmaf(pv[i][k], vv.x, acc[i].x);
                    acc[i].y = fmaf(pv[i][k], vv.y, acc[i].y);
                    acc[i].z = fmaf(pv[i][k], vv.z, acc[i].z);
                    acc[i].w = fmaf(pv[i][k], vv.w, acc[i].w);
                }
            }
        }
    }

    // ================= epilogue: ALL global stores nontemporal, no barriers =================

    // output [B][L][H][E]
    #pragma unroll
    for (int i = 0; i < 4; ++i) {
        int row = 16 * wv + r4 + 4 * i;
        float* dst = outp + ((size_t)(b * Lq + R0 + row) * Hq + h) * Eq + d4 * 4;
        nt_store4(dst, acc[i].x, acc[i].y, acc[i].z, acc[i].w);
    }

    // diagonal attn block: coalesced float4 nt stores, gather from permuted Sp
    #pragma unroll 4
    for (int i = 0; i < 16; ++i) {
        int idx = i * 256 + t, row = idx >> 6, c4 = idx & 63, c = c4 * 4;
        int basep = row * SP_STRIDE + (c & 0xC0) + ((c >> 3) & 7);
        int c7 = c & 7;   // 0 or 4
        nt_store4(ablock + (size_t)row * Lq + qb * 256 + c,
                  bf2f(Sp[basep + (c7 + 0) * 8]),
                  bf2f(Sp[basep + (c7 + 1) * 8]),
                  bf2f(Sp[basep + (c7 + 2) * 8]),
                  bf2f(Sp[basep + (c7 + 3) * 8]));
    }

    // off-block zeros: 64 rows x 448 float4 per wg, lane-contiguous nt stores
    #pragma unroll 4
    for (int i = 0; i < 112; ++i) {
        int f   = i * 256 + t;               // [0, 28672)
        int row = f / 448;                   // magic-mul
        int j   = f - row * 448;
        int c4  = (j < qb64) ? j : j + 64;   // skip diagonal 64 float4s
        nt_store4(ablock + (size_t)row * Lq + c4 * 4, 0.f, 0.f, 0.f, 0.f);
    }
}

extern "C" void kernel_launch(void* const* d_in, const int* in_sizes, int n_in,
                              void* d_out, int out_size, void* d_ws, size_t ws_size,
                              hipStream_t stream) {
    const float* q = (const float*)d_in[0];
    const float* k = (const float*)d_in[1];
    const float* v = (const float*)d_in[2];
    float* out = (float*)d_out;

    const size_t lds_bytes = SP_OFF * sizeof(float) + 64 * SP_STRIDE * sizeof(unsigned short); // 74,752
    (void)hipFuncSetAttribute((const void*)sparse_attn,
                              hipFuncAttributeMaxDynamicSharedMemorySize,
                              (int)lds_bytes);

    dim3 grid(Bq * Hq * 8 * 4);   // 1024 wgs: (b,h,qb,sub)
    dim3 block(256);
    hipLaunchKernelGGL(sparse_attn, grid, block, lds_bytes, stream, q, k, v, out);
}